// Round 11
// baseline (416.899 us; speedup 1.0000x reference)
//
#include <hip/hip_runtime.h>
#include <hip/hip_bf16.h>
#include <math.h>

#define B_  4
#define S_  2048
#define DM  2048
#define H_  16
#define HD_ 128

typedef __bf16 bf16;
typedef __bf16 bf16x4 __attribute__((ext_vector_type(4)));
typedef __bf16 bf16x8 __attribute__((ext_vector_type(8)));
typedef float  f32x4  __attribute__((ext_vector_type(4)));

__device__ __forceinline__ void gload_lds16(const bf16* g, bf16* l) {
  __builtin_amdgcn_global_load_lds(
      (const __attribute__((address_space(1))) void*)g,
      (__attribute__((address_space(3))) void*)l, 16, 0, 0);
}

// ---------------- fused cast fp32 -> bf16 for x + 4 weights ----------------
#define NX4 4194304   // (B*S*DM)/4
#define NW4 1048576   // (DM*DM)/4
__global__ void cast_all(const float* __restrict__ x, const float* __restrict__ wq,
                         const float* __restrict__ wk, const float* __restrict__ wv,
                         const float* __restrict__ wo,
                         bf16* __restrict__ xb, bf16* __restrict__ wqkv,
                         bf16* __restrict__ wob) {
  const int total = NX4 + 4 * NW4;
  int stride = gridDim.x * blockDim.x;
  for (int i = blockIdx.x * blockDim.x + threadIdx.x; i < total; i += stride) {
    const float* src; bf16* dst; int j;
    if (i < NX4) { src = x; dst = xb; j = i; }
    else {
      int t = i - NX4; int r = t >> 20; j = t & (NW4 - 1);
      if      (r == 0) { src = wq; dst = wqkv; }
      else if (r == 1) { src = wk; dst = wqkv + (size_t)NW4 * 4; }
      else if (r == 2) { src = wv; dst = wqkv + (size_t)NW4 * 8; }
      else             { src = wo; dst = wob; }
    }
    float4 v = reinterpret_cast<const float4*>(src)[j];
    bf16x4 o = { (bf16)v.x, (bf16)v.y, (bf16)v.z, (bf16)v.w };
    reinterpret_cast<bf16x4*>(dst)[j] = o;
  }
}

// ---------------- RoPE cos/sin table: tab[s][i] = {cos, sin} ----------------
__global__ void rope_table_k(float* __restrict__ tab) {
  int idx = blockIdx.x * blockDim.x + threadIdx.x;
  if (idx >= S_ * (HD_ / 2)) return;
  int pos = idx >> 6, i = idx & 63;
  float inv = powf(10000.0f, -(2.0f * i) / (float)HD_);
  float ang = (float)pos * inv;
  tab[2 * idx]     = cosf(ang);
  tab[2 * idx + 1] = sinf(ang);
}

// ---------------- deep 4-phase 16x16 bf16 GEMM (m201 lockstep) ----------------
// BM=BN=256, BK=64, 8 waves (2M x 4N). Two 64KB buffers, K-half slots
// [kh][256r][64B], swizzle ((r>>1)&3)<<4 (0-conflict, measured R6-R10).
// Per K-tile 4 phases, m201 discipline {reads; stage; (gate); barrier; MFMA; barrier}:
//  ph0: A[qm0]+B (kh0); stage A-Khi(kt+1)
//  ph1: A[qm1] (B reused); stage B-Khi(kt+1); gate vmcnt(8)
//  ph2: A[qm0]+B (kh1); stage A-Klo(kt+2)
//  ph3: A[qm1] (B reused); stage B-Klo(kt+2); gate vmcnt(8)
// 24 ds_read_b128 + 8 gloads + 8 barriers + 2 counted vmcnt per K-tile.
// EPI=0: fused QKV epilogue (rope-Q / rope-K / transpose-V); EPI=1: f32 + bias.
template<int EPI>
__global__ __launch_bounds__(512, 2)
void gemm16d(const bf16* __restrict__ A, const bf16* __restrict__ Bt,
             bf16* __restrict__ Oq, bf16* __restrict__ Ok, bf16* __restrict__ Ovt,
             float* __restrict__ Cf, const float* __restrict__ bias,
             const float* __restrict__ tab, int N, int K) {
  __shared__ char lds[131072];
  const int tid = threadIdx.x;
  const int w = tid >> 6, l = tid & 63;
  const int lr = l & 15, lg = l >> 4;
  const int wm = w >> 2, wn = w & 3;            // 2M x 4N wave grid
  const int row0 = blockIdx.y * 256, col0 = blockIdx.x * 256;
  const int NT = K >> 6;

  // stage one 16KB K-half slot of K-tile kt2 (2 gloads/wave)
  auto stageSlot = [&](int isB, int kh, int kt2) {
    const bf16* src = isB ? (Bt + (size_t)col0 * K) : (A + (size_t)row0 * K);
    char* dstbase = (char*)lds + (kt2 & 1) * 65536 + isB * 32768 + kh * 16384;
    const int kcol = kt2 * 64 + kh * 32;
#pragma unroll
    for (int u = 0; u < 2; ++u) {
      int D = w * 2048 + u * 1024 + l * 16;
      int r = D >> 6, cb = D & 63;
      int sc = cb ^ (((r >> 1) & 3) << 4);      // pre-swizzled source col byte
      gload_lds16(src + (size_t)r * K + kcol + (sc >> 1),
                  (bf16*)(dstbase + w * 2048 + u * 1024));
    }
  };

  const int swzt = ((lr >> 1) & 3) << 4;
  int offA[2][4], offB[4];
#pragma unroll
  for (int qm = 0; qm < 2; ++qm)
#pragma unroll
    for (int mi = 0; mi < 4; ++mi) {
      int r = wm * 128 + qm * 64 + mi * 16 + lr;
      offA[qm][mi] = r * 64 + ((lg * 16) ^ swzt);
    }
#pragma unroll
  for (int ni = 0; ni < 4; ++ni) {
    int r = wn * 64 + ni * 16 + lr;
    offB[ni] = 32768 + r * 64 + ((lg * 16) ^ swzt);
  }

  f32x4 acc[8][4] = {};

  // prologue: Klo(0), Khi(0), Klo(1)  (12 loads; issue order matters for vmcnt)
  stageSlot(0, 0, 0); stageSlot(1, 0, 0);
  stageSlot(0, 1, 0); stageSlot(1, 1, 0);
  if (NT > 1) { stageSlot(0, 0, 1); stageSlot(1, 0, 1); }
  asm volatile("s_waitcnt vmcnt(8)" ::: "memory");   // Klo(0) landed
  __builtin_amdgcn_s_barrier();

#pragma unroll 1
  for (int kt = 0; kt < NT; ++kt) {
    const char* bufb = (const char*)lds + (kt & 1) * 65536;
#pragma unroll
    for (int kh = 0; kh < 2; ++kh) {
      const char* bb = bufb + kh * 16384;
      bf16x8 af[4], bfr[4];
      // ---- phase 2*kh: A[qm0] + B reads; stage A-slot; barrier; MFMA; barrier ----
#pragma unroll
      for (int ni = 0; ni < 4; ++ni)
        bfr[ni] = *reinterpret_cast<const bf16x8*>(bb + offB[ni]);
#pragma unroll
      for (int mi = 0; mi < 4; ++mi)
        af[mi] = *reinterpret_cast<const bf16x8*>(bb + offA[0][mi]);
      if (kh == 0) { if (kt + 1 < NT) stageSlot(0, 1, kt + 1); }
      else         { if (kt + 2 < NT) stageSlot(0, 0, kt + 2); }
      __builtin_amdgcn_s_barrier();
      __builtin_amdgcn_s_setprio(1);
#pragma unroll
      for (int mi = 0; mi < 4; ++mi)
#pragma unroll
        for (int ni = 0; ni < 4; ++ni)
          acc[mi][ni] = __builtin_amdgcn_mfma_f32_16x16x32_bf16(af[mi], bfr[ni], acc[mi][ni], 0, 0, 0);
      __builtin_amdgcn_s_setprio(0);
      __builtin_amdgcn_s_barrier();
      // ---- phase 2*kh+1: A[qm1] reads (B reused); stage B-slot; gate; barrier; MFMA; barrier ----
#pragma unroll
      for (int mi = 0; mi < 4; ++mi)
        af[mi] = *reinterpret_cast<const bf16x8*>(bb + offA[1][mi]);
      if (kh == 0) {
        if (kt + 1 < NT) stageSlot(1, 1, kt + 1);
        if (kt == NT - 1) asm volatile("s_waitcnt vmcnt(0)" ::: "memory");
        else              asm volatile("s_waitcnt vmcnt(8)" ::: "memory");
      } else {
        if (kt + 2 < NT) stageSlot(1, 0, kt + 2);
        if (kt < NT - 1) {
          if (kt == NT - 2) asm volatile("s_waitcnt vmcnt(4)" ::: "memory");
          else              asm volatile("s_waitcnt vmcnt(8)" ::: "memory");
        }
      }
      __builtin_amdgcn_s_barrier();
      __builtin_amdgcn_s_setprio(1);
#pragma unroll
      for (int mi = 0; mi < 4; ++mi)
#pragma unroll
        for (int ni = 0; ni < 4; ++ni)
          acc[4 + mi][ni] = __builtin_amdgcn_mfma_f32_16x16x32_bf16(af[mi], bfr[ni], acc[4 + mi][ni], 0, 0, 0);
      __builtin_amdgcn_s_setprio(0);
      __builtin_amdgcn_s_barrier();
    }
  }

  // ---- epilogue: acc[qm*4+mi][ni] -> rows row0+wm*128+qm*64+mi*16, cols wn*64+ni*16 ----
#pragma unroll
  for (int ai = 0; ai < 8; ++ai) {
    int rb = row0 + wm * 128 + ai * 16 + lg * 4;
#pragma unroll
    for (int ni = 0; ni < 4; ++ni) {
      int gc = col0 + wn * 64 + ni * 16 + lr;
      if (EPI == 1) {
#pragma unroll
        for (int j = 0; j < 4; ++j)
          Cf[(size_t)(rb + j) * N + gc] = acc[ai][ni][j] + bias[gc];
      } else {
        int reg = col0 >> 11;     // uniform per block: 0=Q, 1=K, 2=V
        int cc = gc & 2047;
        if (reg == 2) {
          int bb2 = rb >> 11, ss = rb & 2047;
          int hh = cc >> 7, dd = cc & 127;
          bf16x4 pack = { (bf16)acc[ai][ni][0], (bf16)acc[ai][ni][1],
                          (bf16)acc[ai][ni][2], (bf16)acc[ai][ni][3] };
          *reinterpret_cast<bf16x4*>(Ovt + (((size_t)(bb2 * H_ + hh) * HD_ + dd) << 11) + ss) = pack;
        } else {
          bf16* Dst = (reg == 0) ? Oq : Ok;
          float scale = (reg == 0) ? 0.08838834764831845f : 1.0f;
          int i2 = (cc & 127) >> 1;
          float sgn = (lr & 1) ? 1.0f : -1.0f;
#pragma unroll
          for (int j = 0; j < 4; ++j) {
            float own = acc[ai][ni][j];
            float par = __shfl_xor(own, 1);
            int ss = (rb + j) & (S_ - 1);
            float2 cs = reinterpret_cast<const float2*>(tab)[ss * 64 + i2];
            Dst[(size_t)(rb + j) * 2048 + cc] = (bf16)((own * cs.x + sgn * par * cs.y) * scale);
          }
        }
      }
    }
  }
}

// ---------------- causal flash attention (unchanged from R8) ----------------
__global__ __launch_bounds__(512, 4)
void attn_fwd(const bf16* __restrict__ Q, const bf16* __restrict__ K,
              const bf16* __restrict__ Vt, bf16* __restrict__ O) {
  __shared__ bf16 Ks[2][64 * 128];
  __shared__ bf16 Vs[2][128 * 64];
  __shared__ bf16 Ps[8][16 * 64];
  const int tid = threadIdx.x;
  const int w = tid >> 6, l = tid & 63;
  const int lr = l & 15, lg = l >> 4;
  const int L = blockIdx.x + 8 * (blockIdx.y + 16 * blockIdx.z);
  const int xcd = L & 7, s = L >> 3;
  const int p = xcd * 8 + (s & 7);
  const int bx = s >> 3;
  const int h = p & 15, b = p >> 4;
  const size_t bbase = (size_t)b * S_ * DM + (size_t)h * HD_;
  const bf16* vtb = Vt + (size_t)(b * H_ + h) * HD_ * S_;

#pragma unroll 1
  for (int pass = 0; pass < 2; ++pass) {
    const int qt = pass ? bx : (15 - bx);
    const int q0 = qt * 128 + w * 16;
    const int ktmax = 2 * qt + 1;

    bf16x8 qf[4];
#pragma unroll
    for (int kb = 0; kb < 4; ++kb)
      qf[kb] = *reinterpret_cast<const bf16x8*>(Q + bbase + (size_t)(q0 + lr) * DM + kb * 32 + lg * 8);

    float m_r = -INFINITY;
    float l_r = 0.f;
    f32x4 o[8] = {};

#pragma unroll
    for (int i = 0; i < 2; ++i) {
      int X = w * 2048 + i * 1024 + l * 16;
      int r = X >> 8, scb = (X & 255) ^ ((r & 7) << 4);
      gload_lds16(K + bbase + (size_t)r * DM + (scb >> 1), &Ks[0][(w * 2048 + i * 1024) >> 1]);
    }
#pragma unroll
    for (int i = 0; i < 2; ++i) {
      int X = w * 2048 + i * 1024 + l * 16;
      int d = X >> 7, scb = (X & 127) ^ ((d & 7) << 4);
      gload_lds16(vtb + (size_t)d * S_ + (scb >> 1), &Vs[0][(w * 2048 + i * 1024) >> 1]);
    }

    for (int kt = 0; kt <= ktmax; ++kt) {
      const int buf = kt & 1;
      if (kt < ktmax) {
        const int nk = (kt + 1) * 64;
#pragma unroll
        for (int i = 0; i < 2; ++i) {
          int X = w * 2048 + i * 1024 + l * 16;
          int r = X >> 8, scb = (X & 255) ^ ((r & 7) << 4);
          gload_lds16(K + bbase + (size_t)(nk + r) * DM + (scb >> 1),
                      &Ks[buf ^ 1][(w * 2048 + i * 1024) >> 1]);
        }
#pragma unroll
        for (int i = 0; i < 2; ++i) {
          int X = w * 2048 + i * 1024 + l * 16;
          int d = X >> 7, scb = (X & 127) ^ ((d & 7) << 4);
          gload_lds16(vtb + (size_t)d * S_ + nk + (scb >> 1),
                      &Vs[buf ^ 1][(w * 2048 + i * 1024) >> 1]);
        }
        asm volatile("s_waitcnt vmcnt(4)" ::: "memory");
      } else {
        asm volatile("s_waitcnt vmcnt(0)" ::: "memory");
      }
      __builtin_amdgcn_s_barrier();

      f32x4 sc4[4];
      __builtin_amdgcn_s_setprio(1);
#pragma unroll
      for (int cb = 0; cb < 4; ++cb) {
        sc4[cb] = f32x4{0.f, 0.f, 0.f, 0.f};
        int r = cb * 16 + lr;
#pragma unroll
        for (int kb = 0; kb < 4; ++kb) {
          int off = r * 256 + ((kb * 64 + lg * 16) ^ ((lr & 7) << 4));
          bf16x8 kf = *reinterpret_cast<const bf16x8*>((const char*)Ks[buf] + off);
          sc4[cb] = __builtin_amdgcn_mfma_f32_16x16x32_bf16(kf, qf[kb], sc4[cb], 0, 0, 0);
        }
      }
      __builtin_amdgcn_s_setprio(0);

      const int kv0 = kt * 64;
      if (kv0 + 63 > q0) {
        const int qq = q0 + lr;
#pragma unroll
        for (int cb = 0; cb < 4; ++cb)
#pragma unroll
          for (int jj = 0; jj < 4; ++jj)
            if (kv0 + cb * 16 + lg * 4 + jj > qq) sc4[cb][jj] = -INFINITY;
      }

      float tm = -INFINITY;
#pragma unroll
      for (int cb = 0; cb < 4; ++cb)
#pragma unroll
        for (int jj = 0; jj < 4; ++jj) tm = fmaxf(tm, sc4[cb][jj]);
      tm = fmaxf(tm, __shfl_xor(tm, 16));
      tm = fmaxf(tm, __shfl_xor(tm, 32));
      const bool resc = !__all(tm <= m_r + 8.0f);
      float sc_f = 1.f;
      if (resc) {
        float mnew = fmaxf(m_r, tm);
        sc_f = __expf(m_r - mnew);
        m_r = mnew;
      }
      float rs = 0.f;
#pragma unroll
      for (int cb = 0; cb < 4; ++cb)
#pragma unroll
        for (int jj = 0; jj < 4; ++jj) {
          float pp = __expf(sc4[cb][jj] - m_r);
          sc4[cb][jj] = pp;
          rs += pp;
        }
      rs += __shfl_xor(rs, 16);
      rs += __shfl_xor(rs, 32);
      l_r = l_r * sc_f + rs;
      if (resc) {
        float scO[4];
#pragma unroll
        for (int j = 0; j < 4; ++j) scO[j] = __shfl(sc_f, lg * 4 + j);
#pragma unroll
        for (int nb = 0; nb < 8; ++nb)
#pragma unroll
          for (int j = 0; j < 4; ++j) o[nb][j] *= scO[j];
      }

#pragma unroll
      for (int cb = 0; cb < 4; ++cb) {
        bf16x4 pk = { (bf16)sc4[cb][0], (bf16)sc4[cb][1], (bf16)sc4[cb][2], (bf16)sc4[cb][3] };
        int off = lr * 128 + ((cb * 32 + lg * 8) ^ ((lr & 7) << 4));
        *reinterpret_cast<bf16x4*>((char*)Ps[w] + off) = pk;
      }

      bf16x8 pf[2];
#pragma unroll
      for (int kc = 0; kc < 2; ++kc) {
        int off = lr * 128 + ((kc * 64 + lg * 16) ^ ((lr & 7) << 4));
        pf[kc] = *reinterpret_cast<const bf16x8*>((const char*)Ps[w] + off);
      }
      __builtin_amdgcn_s_setprio(1);
#pragma unroll
      for (int nb = 0; nb < 8; ++nb) {
        int d = nb * 16 + lr;
#pragma unroll
        for (int kc = 0; kc < 2; ++kc) {
          int off = d * 128 + ((kc * 64 + lg * 16) ^ ((lr & 7) << 4));
          bf16x8 vf = *reinterpret_cast<const bf16x8*>((const char*)Vs[buf] + off);
          o[nb] = __builtin_amdgcn_mfma_f32_16x16x32_bf16(pf[kc], vf, o[nb], 0, 0, 0);
        }
      }
      __builtin_amdgcn_s_setprio(0);

      asm volatile("s_waitcnt lgkmcnt(0)" ::: "memory");
      __builtin_amdgcn_s_barrier();
    }

    float lO[4];
#pragma unroll
    for (int j = 0; j < 4; ++j) lO[j] = __shfl(l_r, lg * 4 + j);
#pragma unroll
    for (int j = 0; j < 4; ++j) {
      float inv = 1.0f / lO[j];
      size_t rowoff = bbase + (size_t)(q0 + lg * 4 + j) * DM;
#pragma unroll
      for (int nb = 0; nb < 8; ++nb)
        O[rowoff + nb * 16 + lr] = (bf16)(o[nb][j] * inv);
    }
  }
}

extern "C" void kernel_launch(void* const* d_in, const int* in_sizes, int n_in,
                              void* d_out, int out_size, void* d_ws, size_t ws_size,
                              hipStream_t stream) {
  const float* x  = (const float*)d_in[0];
  const float* Wq = (const float*)d_in[1];
  const float* Wk = (const float*)d_in[2];
  const float* Wv = (const float*)d_in[3];
  const float* Wo = (const float*)d_in[4];
  const float* bo = (const float*)d_in[5];
  float* out = (float*)d_out;

  const size_t NX = (size_t)B_ * S_ * DM;  // 16,777,216
  const size_t NW = (size_t)DM * DM;       //  4,194,304
  char* ws = (char*)d_ws;
  bf16* xb   = (bf16*)ws; ws += NX * 2;
  bf16* wqkv = (bf16*)ws; ws += 3 * NW * 2;  // [Wq;Wk;Wv] as one [6144][2048]
  bf16* wob  = (bf16*)ws; ws += NW * 2;
  bf16* qb   = (bf16*)ws; ws += NX * 2;
  bf16* kb   = (bf16*)ws; ws += NX * 2;
  bf16* vt   = (bf16*)ws; ws += NX * 2;   // V pre-transposed [B][H][HD][S]
  bf16* ctxb = (bf16*)ws; ws += NX * 2;
  float* tab = (float*)ws; ws += (size_t)S_ * 64 * 2 * sizeof(float);

  cast_all<<<2048, 256, 0, stream>>>(x, Wq, Wk, Wv, Wo, xb, wqkv, wob);
  rope_table_k<<<(S_ * 64 + 255) / 256, 256, 0, stream>>>(tab);

  const int M = B_ * S_;
  // fused QKV projection + RoPE + V-transpose: C[8192][6144]
  gemm16d<0><<<dim3(3 * DM / 256, M / 256), 512, 0, stream>>>(
      xb, wqkv, qb, kb, vt, nullptr, nullptr, tab, 3 * DM, DM);

  attn_fwd<<<dim3(8, H_, B_), 512, 0, stream>>>(qb, kb, vt, ctxb);

  // output projection + bias (f32 out)
  gemm16d<1><<<dim3(DM / 256, M / 256), 512, 0, stream>>>(
      ctxb, wob, nullptr, nullptr, nullptr, out, bo, nullptr, DM, DM);
}

// Round 14
// 406.315 us; speedup vs baseline: 1.0260x; 1.0260x over previous
//
#include <hip/hip_runtime.h>
#include <hip/hip_bf16.h>
#include <math.h>

#define B_  4
#define S_  2048
#define DM  2048
#define H_  16
#define HD_ 128

typedef __bf16 bf16;
typedef __bf16 bf16x4 __attribute__((ext_vector_type(4)));
typedef __bf16 bf16x8 __attribute__((ext_vector_type(8)));
typedef float  f32x4  __attribute__((ext_vector_type(4)));

__device__ __forceinline__ void gload_lds16(const bf16* g, bf16* l) {
  __builtin_amdgcn_global_load_lds(
      (const __attribute__((address_space(1))) void*)g,
      (__attribute__((address_space(3))) void*)l, 16, 0, 0);
}

// ---------------- fused cast fp32 -> bf16 for x + 4 weights ----------------
#define NX4 4194304   // (B*S*DM)/4
#define NW4 1048576   // (DM*DM)/4
__global__ void cast_all(const float* __restrict__ x, const float* __restrict__ wq,
                         const float* __restrict__ wk, const float* __restrict__ wv,
                         const float* __restrict__ wo,
                         bf16* __restrict__ xb, bf16* __restrict__ wqkv,
                         bf16* __restrict__ wob) {
  const int total = NX4 + 4 * NW4;
  int stride = gridDim.x * blockDim.x;
  for (int i = blockIdx.x * blockDim.x + threadIdx.x; i < total; i += stride) {
    const float* src; bf16* dst; int j;
    if (i < NX4) { src = x; dst = xb; j = i; }
    else {
      int t = i - NX4; int r = t >> 20; j = t & (NW4 - 1);
      if      (r == 0) { src = wq; dst = wqkv; }
      else if (r == 1) { src = wk; dst = wqkv + (size_t)NW4 * 4; }
      else if (r == 2) { src = wv; dst = wqkv + (size_t)NW4 * 8; }
      else             { src = wo; dst = wob; }
    }
    float4 v = reinterpret_cast<const float4*>(src)[j];
    bf16x4 o = { (bf16)v.x, (bf16)v.y, (bf16)v.z, (bf16)v.w };
    reinterpret_cast<bf16x4*>(dst)[j] = o;
  }
}

// ---------------- RoPE cos/sin table: tab[s][i] = {cos, sin} ----------------
__global__ void rope_table_k(float* __restrict__ tab) {
  int idx = blockIdx.x * blockDim.x + threadIdx.x;
  if (idx >= S_ * (HD_ / 2)) return;
  int pos = idx >> 6, i = idx & 63;
  float inv = powf(10000.0f, -(2.0f * i) / (float)HD_);
  float ang = (float)pos * inv;
  tab[2 * idx]     = cosf(ang);
  tab[2 * idx + 1] = sinf(ang);
}

// ---------------- deep 4-phase 16x16 bf16 GEMM (R10 schedule, measured best) ----------------
template<int EPI>
__global__ __launch_bounds__(512, 2)
void gemm16d(const bf16* __restrict__ A, const bf16* __restrict__ Bt,
             bf16* __restrict__ Oq, bf16* __restrict__ Ok, bf16* __restrict__ Ovt,
             float* __restrict__ Cf, const float* __restrict__ bias,
             const float* __restrict__ tab, int N, int K) {
  __shared__ char lds[131072];
  const int tid = threadIdx.x;
  const int w = tid >> 6, l = tid & 63;
  const int lr = l & 15, lg = l >> 4;
  const int wm = w >> 2, wn = w & 3;            // 2M x 4N wave grid
  const int row0 = blockIdx.y * 256, col0 = blockIdx.x * 256;
  const int NT = K >> 6;

  auto stageSlot = [&](int isB, int kh, int kt2) {
    const bf16* src = isB ? (Bt + (size_t)col0 * K) : (A + (size_t)row0 * K);
    char* dstbase = (char*)lds + (kt2 & 1) * 65536 + isB * 32768 + kh * 16384;
    const int kcol = kt2 * 64 + kh * 32;
#pragma unroll
    for (int u = 0; u < 2; ++u) {
      int D = w * 2048 + u * 1024 + l * 16;
      int r = D >> 6, cb = D & 63;
      int sc = cb ^ (((r >> 1) & 3) << 4);
      gload_lds16(src + (size_t)r * K + kcol + (sc >> 1),
                  (bf16*)(dstbase + w * 2048 + u * 1024));
    }
  };

  const int swzt = ((lr >> 1) & 3) << 4;
  int offA[2][4], offB[4];
#pragma unroll
  for (int qm = 0; qm < 2; ++qm)
#pragma unroll
    for (int mi = 0; mi < 4; ++mi) {
      int r = wm * 128 + qm * 64 + mi * 16 + lr;
      offA[qm][mi] = r * 64 + ((lg * 16) ^ swzt);
    }
#pragma unroll
  for (int ni = 0; ni < 4; ++ni) {
    int r = wn * 64 + ni * 16 + lr;
    offB[ni] = 32768 + r * 64 + ((lg * 16) ^ swzt);
  }

  f32x4 acc[8][4] = {};

  stageSlot(0, 0, 0); stageSlot(1, 0, 0);
  stageSlot(0, 1, 0); stageSlot(1, 1, 0);
  if (NT > 1) { stageSlot(0, 0, 1); stageSlot(1, 0, 1); }
  asm volatile("s_waitcnt vmcnt(8)" ::: "memory");
  __builtin_amdgcn_s_barrier();

#pragma unroll 1
  for (int kt = 0; kt < NT; ++kt) {
    const char* bufb = (const char*)lds + (kt & 1) * 65536;
#pragma unroll
    for (int kh = 0; kh < 2; ++kh) {
      const char* bb = bufb + kh * 16384;
      bf16x8 af[4], bfr[4];
#pragma unroll
      for (int ni = 0; ni < 4; ++ni)
        bfr[ni] = *reinterpret_cast<const bf16x8*>(bb + offB[ni]);
#pragma unroll
      for (int mi = 0; mi < 4; ++mi)
        af[mi] = *reinterpret_cast<const bf16x8*>(bb + offA[0][mi]);
      if (kh == 0) { if (kt + 1 < NT) stageSlot(0, 1, kt + 1); }
      else         { if (kt + 2 < NT) stageSlot(0, 0, kt + 2); }
      __builtin_amdgcn_s_barrier();
      __builtin_amdgcn_s_setprio(1);
#pragma unroll
      for (int mi = 0; mi < 4; ++mi)
#pragma unroll
        for (int ni = 0; ni < 4; ++ni)
          acc[mi][ni] = __builtin_amdgcn_mfma_f32_16x16x32_bf16(af[mi], bfr[ni], acc[mi][ni], 0, 0, 0);
      __builtin_amdgcn_s_setprio(0);
#pragma unroll
      for (int mi = 0; mi < 4; ++mi)
        af[mi] = *reinterpret_cast<const bf16x8*>(bb + offA[1][mi]);
      if (kh == 0) {
        if (kt + 1 < NT) stageSlot(1, 1, kt + 1);
        if (kt == NT - 1) asm volatile("s_waitcnt vmcnt(0)" ::: "memory");
        else              asm volatile("s_waitcnt vmcnt(8)" ::: "memory");
      } else {
        if (kt + 2 < NT) stageSlot(1, 0, kt + 2);
        if (kt < NT - 1) {
          if (kt == NT - 2) asm volatile("s_waitcnt vmcnt(4)" ::: "memory");
          else              asm volatile("s_waitcnt vmcnt(8)" ::: "memory");
        }
      }
      __builtin_amdgcn_s_barrier();
      __builtin_amdgcn_s_setprio(1);
#pragma unroll
      for (int mi = 0; mi < 4; ++mi)
#pragma unroll
        for (int ni = 0; ni < 4; ++ni)
          acc[4 + mi][ni] = __builtin_amdgcn_mfma_f32_16x16x32_bf16(af[mi], bfr[ni], acc[4 + mi][ni], 0, 0, 0);
      __builtin_amdgcn_s_setprio(0);
    }
  }

  // ---- epilogue ----
#pragma unroll
  for (int ai = 0; ai < 8; ++ai) {
    int rb = row0 + wm * 128 + ai * 16 + lg * 4;
#pragma unroll
    for (int ni = 0; ni < 4; ++ni) {
      int gc = col0 + wn * 64 + ni * 16 + lr;
      if (EPI == 1) {
#pragma unroll
        for (int j = 0; j < 4; ++j)
          Cf[(size_t)(rb + j) * N + gc] = acc[ai][ni][j] + bias[gc];
      } else {
        int reg = col0 >> 11;     // uniform per block: 0=Q, 1=K, 2=V
        int cc = gc & 2047;
        if (reg == 2) {
          int bb2 = rb >> 11, ss = rb & 2047;
          int hh = cc >> 7, dd = cc & 127;
          bf16x4 pack = { (bf16)acc[ai][ni][0], (bf16)acc[ai][ni][1],
                          (bf16)acc[ai][ni][2], (bf16)acc[ai][ni][3] };
          *reinterpret_cast<bf16x4*>(Ovt + (((size_t)(bb2 * H_ + hh) * HD_ + dd) << 11) + ss) = pack;
        } else {
          bf16* Dst = (reg == 0) ? Oq : Ok;
          float scale = (reg == 0) ? 0.08838834764831845f : 1.0f;
          int i2 = (cc & 127) >> 1;
          float sgn = (lr & 1) ? 1.0f : -1.0f;
#pragma unroll
          for (int j = 0; j < 4; ++j) {
            float own = acc[ai][ni][j];
            float par = __shfl_xor(own, 1);
            int ss = (rb + j) & (S_ - 1);
            float2 cs = reinterpret_cast<const float2*>(tab)[ss * 64 + i2];
            Dst[(size_t)(rb + j) * 2048 + cc] = (bf16)((own * cs.x + sgn * par * cs.y) * scale);
          }
        }
      }
    }
  }
}

// ---------------- causal flash attention: 8 waves x 32 q-rows (QBLK=256) ----------------
// Per KV-tile each wave: K-frags 16 + V-frags 16 read once, 64 MFMA (2x the R8
// ratio). Paired q-tiles: block bx does qt=(7-bx) and bx -> uniform 36 KV-steps.
// Grid 4x16x4 = 256 = 1 block/CU. K/Vt LDS XOR-swizzled, double-buffered,
// counted vmcnt(4). T13 defer-max. XCD co-location of each (b,h).
__global__ __launch_bounds__(512, 2)
void attn_fwd(const bf16* __restrict__ Q, const bf16* __restrict__ K,
              const bf16* __restrict__ Vt, bf16* __restrict__ O) {
  __shared__ bf16 Ks[2][64 * 128];
  __shared__ bf16 Vs[2][128 * 64];
  __shared__ bf16 Ps[8][32 * 64];
  const int tid = threadIdx.x;
  const int w = tid >> 6, l = tid & 63;
  const int lr = l & 15, lg = l >> 4;
  const int L = blockIdx.x + 4 * (blockIdx.y + 16 * blockIdx.z);
  const int xcd = L & 7, s = L >> 3;
  const int p = xcd * 8 + (s & 7);
  const int bx = s >> 3;                 // 0..3
  const int h = p & 15, b = p >> 4;
  const size_t bbase = (size_t)b * S_ * DM + (size_t)h * HD_;
  const bf16* vtb = Vt + (size_t)(b * H_ + h) * HD_ * S_;

#pragma unroll 1
  for (int pass = 0; pass < 2; ++pass) {
    const int qt = pass ? bx : (7 - bx);
    const int q0 = qt * 256 + w * 32;
    const int ktmax = 4 * qt + 3;

    bf16x8 qf[2][4];
#pragma unroll
    for (int qr = 0; qr < 2; ++qr)
#pragma unroll
      for (int kb = 0; kb < 4; ++kb)
        qf[qr][kb] = *reinterpret_cast<const bf16x8*>(
            Q + bbase + (size_t)(q0 + qr * 16 + lr) * DM + kb * 32 + lg * 8);

    float m_r[2] = {-INFINITY, -INFINITY};
    float l_r[2] = {0.f, 0.f};
    f32x4 o[8][2] = {};

    // prologue: stage tile 0 into buf 0
#pragma unroll
    for (int i = 0; i < 2; ++i) {
      int X = w * 2048 + i * 1024 + l * 16;
      int r = X >> 8, scb = (X & 255) ^ ((r & 7) << 4);
      gload_lds16(K + bbase + (size_t)r * DM + (scb >> 1), &Ks[0][(w * 2048 + i * 1024) >> 1]);
    }
#pragma unroll
    for (int i = 0; i < 2; ++i) {
      int X = w * 2048 + i * 1024 + l * 16;
      int d = X >> 7, scb = (X & 127) ^ ((d & 7) << 4);
      gload_lds16(vtb + (size_t)d * S_ + (scb >> 1), &Vs[0][(w * 2048 + i * 1024) >> 1]);
    }

    for (int kt = 0; kt <= ktmax; ++kt) {
      const int buf = kt & 1;
      if (kt < ktmax) {
        const int nk = (kt + 1) * 64;
#pragma unroll
        for (int i = 0; i < 2; ++i) {
          int X = w * 2048 + i * 1024 + l * 16;
          int r = X >> 8, scb = (X & 255) ^ ((r & 7) << 4);
          gload_lds16(K + bbase + (size_t)(nk + r) * DM + (scb >> 1),
                      &Ks[buf ^ 1][(w * 2048 + i * 1024) >> 1]);
        }
#pragma unroll
        for (int i = 0; i < 2; ++i) {
          int X = w * 2048 + i * 1024 + l * 16;
          int d = X >> 7, scb = (X & 127) ^ ((d & 7) << 4);
          gload_lds16(vtb + (size_t)d * S_ + nk + (scb >> 1),
                      &Vs[buf ^ 1][(w * 2048 + i * 1024) >> 1]);
        }
        asm volatile("s_waitcnt vmcnt(4)" ::: "memory");
      } else {
        asm volatile("s_waitcnt vmcnt(0)" ::: "memory");
      }
      __builtin_amdgcn_s_barrier();

      // ---- swapped QK^T: K-frags read once, used for both qr halves ----
      f32x4 sc4[4][2];
      __builtin_amdgcn_s_setprio(1);
#pragma unroll
      for (int cb = 0; cb < 4; ++cb) {
        sc4[cb][0] = f32x4{0.f, 0.f, 0.f, 0.f};
        sc4[cb][1] = f32x4{0.f, 0.f, 0.f, 0.f};
        int r = cb * 16 + lr;
#pragma unroll
        for (int kb = 0; kb < 4; ++kb) {
          int off = r * 256 + ((kb * 64 + lg * 16) ^ ((lr & 7) << 4));
          bf16x8 kf = *reinterpret_cast<const bf16x8*>((const char*)Ks[buf] + off);
          sc4[cb][0] = __builtin_amdgcn_mfma_f32_16x16x32_bf16(kf, qf[0][kb], sc4[cb][0], 0, 0, 0);
          sc4[cb][1] = __builtin_amdgcn_mfma_f32_16x16x32_bf16(kf, qf[1][kb], sc4[cb][1], 0, 0, 0);
        }
      }
      __builtin_amdgcn_s_setprio(0);

      // ---- causal mask: kv = kv0+cb*16+lg*4+jj ; q = q0+qr*16+lr ----
      const int kv0 = kt * 64;
      if (kv0 + 63 > q0) {
#pragma unroll
        for (int qr = 0; qr < 2; ++qr) {
          const int qq = q0 + qr * 16 + lr;
#pragma unroll
          for (int cb = 0; cb < 4; ++cb)
#pragma unroll
            for (int jj = 0; jj < 4; ++jj)
              if (kv0 + cb * 16 + lg * 4 + jj > qq) sc4[cb][qr][jj] = -INFINITY;
        }
      }

      // ---- online softmax (two row-states per lane) with defer-max ----
      float tm[2] = {-INFINITY, -INFINITY};
#pragma unroll
      for (int qr = 0; qr < 2; ++qr) {
#pragma unroll
        for (int cb = 0; cb < 4; ++cb)
#pragma unroll
          for (int jj = 0; jj < 4; ++jj) tm[qr] = fmaxf(tm[qr], sc4[cb][qr][jj]);
        tm[qr] = fmaxf(tm[qr], __shfl_xor(tm[qr], 16));
        tm[qr] = fmaxf(tm[qr], __shfl_xor(tm[qr], 32));
      }
      const bool resc = !__all(fmaxf(tm[0] - m_r[0], tm[1] - m_r[1]) <= 8.0f);
      float sc_f[2] = {1.f, 1.f};
      if (resc) {
#pragma unroll
        for (int qr = 0; qr < 2; ++qr) {
          float mnew = fmaxf(m_r[qr], tm[qr]);
          sc_f[qr] = __expf(m_r[qr] - mnew);
          m_r[qr] = mnew;
        }
      }
#pragma unroll
      for (int qr = 0; qr < 2; ++qr) {
        float rs = 0.f;
#pragma unroll
        for (int cb = 0; cb < 4; ++cb)
#pragma unroll
          for (int jj = 0; jj < 4; ++jj) {
            float pp = __expf(sc4[cb][qr][jj] - m_r[qr]);
            sc4[cb][qr][jj] = pp;
            rs += pp;
          }
        rs += __shfl_xor(rs, 16);
        rs += __shfl_xor(rs, 32);
        l_r[qr] = l_r[qr] * sc_f[qr] + rs;
      }
      if (resc) {
#pragma unroll
        for (int qr = 0; qr < 2; ++qr) {
          float scO[4];
#pragma unroll
          for (int j = 0; j < 4; ++j) scO[j] = __shfl(sc_f[qr], lg * 4 + j);
#pragma unroll
          for (int nb = 0; nb < 8; ++nb)
#pragma unroll
            for (int j = 0; j < 4; ++j) o[nb][qr][j] *= scO[j];
        }
      }

      // ---- P -> LDS (rows q = qr*16+lr of [32][64], swizzled) ----
#pragma unroll
      for (int qr = 0; qr < 2; ++qr)
#pragma unroll
        for (int cb = 0; cb < 4; ++cb) {
          bf16x4 pk = { (bf16)sc4[cb][qr][0], (bf16)sc4[cb][qr][1],
                        (bf16)sc4[cb][qr][2], (bf16)sc4[cb][qr][3] };
          int off = (qr * 16 + lr) * 128 + ((cb * 32 + lg * 8) ^ ((lr & 7) << 4));
          *reinterpret_cast<bf16x4*>((char*)Ps[w] + off) = pk;
        }

      // ---- PV: V-frags read once, used for both qr halves ----
      bf16x8 pf[2][2];
#pragma unroll
      for (int qr = 0; qr < 2; ++qr)
#pragma unroll
        for (int kc = 0; kc < 2; ++kc) {
          int off = (qr * 16 + lr) * 128 + ((kc * 64 + lg * 16) ^ ((lr & 7) << 4));
          pf[qr][kc] = *reinterpret_cast<const bf16x8*>((const char*)Ps[w] + off);
        }
      __builtin_amdgcn_s_setprio(1);
#pragma unroll
      for (int nb = 0; nb < 8; ++nb) {
        int d = nb * 16 + lr;
#pragma unroll
        for (int kc = 0; kc < 2; ++kc) {
          int off = d * 128 + ((kc * 64 + lg * 16) ^ ((lr & 7) << 4));
          bf16x8 vf = *reinterpret_cast<const bf16x8*>((const char*)Vs[buf] + off);
          o[nb][0] = __builtin_amdgcn_mfma_f32_16x16x32_bf16(pf[0][kc], vf, o[nb][0], 0, 0, 0);
          o[nb][1] = __builtin_amdgcn_mfma_f32_16x16x32_bf16(pf[1][kc], vf, o[nb][1], 0, 0, 0);
        }
      }
      __builtin_amdgcn_s_setprio(0);

      asm volatile("s_waitcnt lgkmcnt(0)" ::: "memory");
      __builtin_amdgcn_s_barrier();
    }

    // ---- epilogue ----
#pragma unroll
    for (int qr = 0; qr < 2; ++qr) {
      float lO[4];
#pragma unroll
      for (int j = 0; j < 4; ++j) lO[j] = __shfl(l_r[qr], lg * 4 + j);
#pragma unroll
      for (int j = 0; j < 4; ++j) {
        float inv = 1.0f / lO[j];
        size_t rowoff = bbase + (size_t)(q0 + qr * 16 + lg * 4 + j) * DM;
#pragma unroll
        for (int nb = 0; nb < 8; ++nb)
          O[rowoff + nb * 16 + lr] = (bf16)(o[nb][qr][j] * inv);
      }
    }
  }
}

extern "C" void kernel_launch(void* const* d_in, const int* in_sizes, int n_in,
                              void* d_out, int out_size, void* d_ws, size_t ws_size,
                              hipStream_t stream) {
  const float* x  = (const float*)d_in[0];
  const float* Wq = (const float*)d_in[1];
  const float* Wk = (const float*)d_in[2];
  const float* Wv = (const float*)d_in[3];
  const float* Wo = (const float*)d_in[4];
  const float* bo = (const float*)d_in[5];
  float* out = (float*)d_out;

  const size_t NX = (size_t)B_ * S_ * DM;  // 16,777,216
  const size_t NW = (size_t)DM * DM;       //  4,194,304
  char* ws = (char*)d_ws;
  bf16* xb   = (bf16*)ws; ws += NX * 2;
  bf16* wqkv = (bf16*)ws; ws += 3 * NW * 2;  // [Wq;Wk;Wv] as one [6144][2048]
  bf16* wob  = (bf16*)ws; ws += NW * 2;
  bf16* qb   = (bf16*)ws; ws += NX * 2;
  bf16* kb   = (bf16*)ws; ws += NX * 2;
  bf16* vt   = (bf16*)ws; ws += NX * 2;   // V pre-transposed [B][H][HD][S]
  bf16* ctxb = (bf16*)ws; ws += NX * 2;
  float* tab = (float*)ws; ws += (size_t)S_ * 64 * 2 * sizeof(float);

  cast_all<<<2048, 256, 0, stream>>>(x, Wq, Wk, Wv, Wo, xb, wqkv, wob);
  rope_table_k<<<(S_ * 64 + 255) / 256, 256, 0, stream>>>(tab);

  const int M = B_ * S_;
  // fused QKV projection + RoPE + V-transpose: C[8192][6144]
  gemm16d<0><<<dim3(3 * DM / 256, M / 256), 512, 0, stream>>>(
      xb, wqkv, qb, kb, vt, nullptr, nullptr, tab, 3 * DM, DM);

  attn_fwd<<<dim3(4, H_, B_), 512, 0, stream>>>(qb, kb, vt, ctxb);

  // output projection + bias (f32 out)
  gemm16d<1><<<dim3(DM / 256, M / 256), 512, 0, stream>>>(
      ctxb, wob, nullptr, nullptr, nullptr, out, bo, nullptr, DM, DM);
}

// Round 15
// 402.624 us; speedup vs baseline: 1.0355x; 1.0092x over previous
//
#include <hip/hip_runtime.h>
#include <hip/hip_bf16.h>
#include <math.h>

#define B_  4
#define S_  2048
#define DM  2048
#define H_  16
#define HD_ 128

typedef __bf16 bf16;
typedef __bf16 bf16x4 __attribute__((ext_vector_type(4)));
typedef __bf16 bf16x8 __attribute__((ext_vector_type(8)));
typedef float  f32x4  __attribute__((ext_vector_type(4)));

__device__ __forceinline__ void gload_lds16(const bf16* g, bf16* l) {
  __builtin_amdgcn_global_load_lds(
      (const __attribute__((address_space(1))) void*)g,
      (__attribute__((address_space(3))) void*)l, 16, 0, 0);
}

// ---------------- fused cast fp32 -> bf16 for x + 4 weights ----------------
#define NX4 4194304   // (B*S*DM)/4
#define NW4 1048576   // (DM*DM)/4
__global__ void cast_all(const float* __restrict__ x, const float* __restrict__ wq,
                         const float* __restrict__ wk, const float* __restrict__ wv,
                         const float* __restrict__ wo,
                         bf16* __restrict__ xb, bf16* __restrict__ wqkv,
                         bf16* __restrict__ wob) {
  const int total = NX4 + 4 * NW4;
  int stride = gridDim.x * blockDim.x;
  for (int i = blockIdx.x * blockDim.x + threadIdx.x; i < total; i += stride) {
    const float* src; bf16* dst; int j;
    if (i < NX4) { src = x; dst = xb; j = i; }
    else {
      int t = i - NX4; int r = t >> 20; j = t & (NW4 - 1);
      if      (r == 0) { src = wq; dst = wqkv; }
      else if (r == 1) { src = wk; dst = wqkv + (size_t)NW4 * 4; }
      else if (r == 2) { src = wv; dst = wqkv + (size_t)NW4 * 8; }
      else             { src = wo; dst = wob; }
    }
    float4 v = reinterpret_cast<const float4*>(src)[j];
    bf16x4 o = { (bf16)v.x, (bf16)v.y, (bf16)v.z, (bf16)v.w };
    reinterpret_cast<bf16x4*>(dst)[j] = o;
  }
}

// ---------------- RoPE cos/sin table: tab[s][i] = {cos, sin} ----------------
__global__ void rope_table_k(float* __restrict__ tab) {
  int idx = blockIdx.x * blockDim.x + threadIdx.x;
  if (idx >= S_ * (HD_ / 2)) return;
  int pos = idx >> 6, i = idx & 63;
  float inv = powf(10000.0f, -(2.0f * i) / (float)HD_);
  float ang = (float)pos * inv;
  tab[2 * idx]     = cosf(ang);
  tab[2 * idx + 1] = sinf(ang);
}

// ---------------- deep 4-phase 16x16 bf16 GEMM (R10 schedule, measured best) ----------------
template<int EPI>
__global__ __launch_bounds__(512, 2)
void gemm16d(const bf16* __restrict__ A, const bf16* __restrict__ Bt,
             bf16* __restrict__ Oq, bf16* __restrict__ Ok, bf16* __restrict__ Ovt,
             float* __restrict__ Cf, const float* __restrict__ bias,
             const float* __restrict__ tab, int N, int K) {
  __shared__ char lds[131072];
  const int tid = threadIdx.x;
  const int w = tid >> 6, l = tid & 63;
  const int lr = l & 15, lg = l >> 4;
  const int wm = w >> 2, wn = w & 3;            // 2M x 4N wave grid
  const int row0 = blockIdx.y * 256, col0 = blockIdx.x * 256;
  const int NT = K >> 6;

  auto stageSlot = [&](int isB, int kh, int kt2) {
    const bf16* src = isB ? (Bt + (size_t)col0 * K) : (A + (size_t)row0 * K);
    char* dstbase = (char*)lds + (kt2 & 1) * 65536 + isB * 32768 + kh * 16384;
    const int kcol = kt2 * 64 + kh * 32;
#pragma unroll
    for (int u = 0; u < 2; ++u) {
      int D = w * 2048 + u * 1024 + l * 16;
      int r = D >> 6, cb = D & 63;
      int sc = cb ^ (((r >> 1) & 3) << 4);
      gload_lds16(src + (size_t)r * K + kcol + (sc >> 1),
                  (bf16*)(dstbase + w * 2048 + u * 1024));
    }
  };

  const int swzt = ((lr >> 1) & 3) << 4;
  int offA[2][4], offB[4];
#pragma unroll
  for (int qm = 0; qm < 2; ++qm)
#pragma unroll
    for (int mi = 0; mi < 4; ++mi) {
      int r = wm * 128 + qm * 64 + mi * 16 + lr;
      offA[qm][mi] = r * 64 + ((lg * 16) ^ swzt);
    }
#pragma unroll
  for (int ni = 0; ni < 4; ++ni) {
    int r = wn * 64 + ni * 16 + lr;
    offB[ni] = 32768 + r * 64 + ((lg * 16) ^ swzt);
  }

  f32x4 acc[8][4] = {};

  stageSlot(0, 0, 0); stageSlot(1, 0, 0);
  stageSlot(0, 1, 0); stageSlot(1, 1, 0);
  if (NT > 1) { stageSlot(0, 0, 1); stageSlot(1, 0, 1); }
  asm volatile("s_waitcnt vmcnt(8)" ::: "memory");
  __builtin_amdgcn_s_barrier();

#pragma unroll 1
  for (int kt = 0; kt < NT; ++kt) {
    const char* bufb = (const char*)lds + (kt & 1) * 65536;
#pragma unroll
    for (int kh = 0; kh < 2; ++kh) {
      const char* bb = bufb + kh * 16384;
      bf16x8 af[4], bfr[4];
#pragma unroll
      for (int ni = 0; ni < 4; ++ni)
        bfr[ni] = *reinterpret_cast<const bf16x8*>(bb + offB[ni]);
#pragma unroll
      for (int mi = 0; mi < 4; ++mi)
        af[mi] = *reinterpret_cast<const bf16x8*>(bb + offA[0][mi]);
      if (kh == 0) { if (kt + 1 < NT) stageSlot(0, 1, kt + 1); }
      else         { if (kt + 2 < NT) stageSlot(0, 0, kt + 2); }
      __builtin_amdgcn_s_barrier();
      __builtin_amdgcn_s_setprio(1);
#pragma unroll
      for (int mi = 0; mi < 4; ++mi)
#pragma unroll
        for (int ni = 0; ni < 4; ++ni)
          acc[mi][ni] = __builtin_amdgcn_mfma_f32_16x16x32_bf16(af[mi], bfr[ni], acc[mi][ni], 0, 0, 0);
      __builtin_amdgcn_s_setprio(0);
#pragma unroll
      for (int mi = 0; mi < 4; ++mi)
        af[mi] = *reinterpret_cast<const bf16x8*>(bb + offA[1][mi]);
      if (kh == 0) {
        if (kt + 1 < NT) stageSlot(1, 1, kt + 1);
        if (kt == NT - 1) asm volatile("s_waitcnt vmcnt(0)" ::: "memory");
        else              asm volatile("s_waitcnt vmcnt(8)" ::: "memory");
      } else {
        if (kt + 2 < NT) stageSlot(1, 0, kt + 2);
        if (kt < NT - 1) {
          if (kt == NT - 2) asm volatile("s_waitcnt vmcnt(4)" ::: "memory");
          else              asm volatile("s_waitcnt vmcnt(8)" ::: "memory");
        }
      }
      __builtin_amdgcn_s_barrier();
      __builtin_amdgcn_s_setprio(1);
#pragma unroll
      for (int mi = 0; mi < 4; ++mi)
#pragma unroll
        for (int ni = 0; ni < 4; ++ni)
          acc[4 + mi][ni] = __builtin_amdgcn_mfma_f32_16x16x32_bf16(af[mi], bfr[ni], acc[4 + mi][ni], 0, 0, 0);
      __builtin_amdgcn_s_setprio(0);
    }
  }

  // ---- epilogue ----
#pragma unroll
  for (int ai = 0; ai < 8; ++ai) {
    int rb = row0 + wm * 128 + ai * 16 + lg * 4;
#pragma unroll
    for (int ni = 0; ni < 4; ++ni) {
      int gc = col0 + wn * 64 + ni * 16 + lr;
      if (EPI == 1) {
#pragma unroll
        for (int j = 0; j < 4; ++j)
          Cf[(size_t)(rb + j) * N + gc] = acc[ai][ni][j] + bias[gc];
      } else {
        int reg = col0 >> 11;     // uniform per block: 0=Q, 1=K, 2=V
        int cc = gc & 2047;
        if (reg == 2) {
          int bb2 = rb >> 11, ss = rb & 2047;
          int hh = cc >> 7, dd = cc & 127;
          bf16x4 pack = { (bf16)acc[ai][ni][0], (bf16)acc[ai][ni][1],
                          (bf16)acc[ai][ni][2], (bf16)acc[ai][ni][3] };
          *reinterpret_cast<bf16x4*>(Ovt + (((size_t)(bb2 * H_ + hh) * HD_ + dd) << 11) + ss) = pack;
        } else {
          bf16* Dst = (reg == 0) ? Oq : Ok;
          float scale = (reg == 0) ? 0.08838834764831845f : 1.0f;
          int i2 = (cc & 127) >> 1;
          float sgn = (lr & 1) ? 1.0f : -1.0f;
#pragma unroll
          for (int j = 0; j < 4; ++j) {
            float own = acc[ai][ni][j];
            float par = __shfl_xor(own, 1);
            int ss = (rb + j) & (S_ - 1);
            float2 cs = reinterpret_cast<const float2*>(tab)[ss * 64 + i2];
            Dst[(size_t)(rb + j) * 2048 + cc] = (bf16)((own * cs.x + sgn * par * cs.y) * scale);
          }
        }
      }
    }
  }
}

// ---------------- causal flash attention (R10/R8 measured-best config) ----------------
// 8 waves x 16 q-rows (QBLK=128), 2 blocks/CU. Paired q-tiles: block bx does
// qt=(15-bx) and bx -> uniform 36 KV-tiles. Swapped QK^T (lane-local P-row),
// XOR-swizzled K/Vt LDS, double-buffered counted vmcnt(4), T13 defer-max,
// XCD co-location of each (b,h). Grid 8x16x4 = 512 = 2 blocks/CU.
__global__ __launch_bounds__(512, 4)
void attn_fwd(const bf16* __restrict__ Q, const bf16* __restrict__ K,
              const bf16* __restrict__ Vt, bf16* __restrict__ O) {
  __shared__ bf16 Ks[2][64 * 128];
  __shared__ bf16 Vs[2][128 * 64];
  __shared__ bf16 Ps[8][16 * 64];
  const int tid = threadIdx.x;
  const int w = tid >> 6, l = tid & 63;
  const int lr = l & 15, lg = l >> 4;
  const int L = blockIdx.x + 8 * (blockIdx.y + 16 * blockIdx.z);
  const int xcd = L & 7, s = L >> 3;
  const int p = xcd * 8 + (s & 7);
  const int bx = s >> 3;
  const int h = p & 15, b = p >> 4;
  const size_t bbase = (size_t)b * S_ * DM + (size_t)h * HD_;
  const bf16* vtb = Vt + (size_t)(b * H_ + h) * HD_ * S_;

#pragma unroll 1
  for (int pass = 0; pass < 2; ++pass) {
    const int qt = pass ? bx : (15 - bx);
    const int q0 = qt * 128 + w * 16;
    const int ktmax = 2 * qt + 1;

    bf16x8 qf[4];
#pragma unroll
    for (int kb = 0; kb < 4; ++kb)
      qf[kb] = *reinterpret_cast<const bf16x8*>(Q + bbase + (size_t)(q0 + lr) * DM + kb * 32 + lg * 8);

    float m_r = -INFINITY;
    float l_r = 0.f;
    f32x4 o[8] = {};

#pragma unroll
    for (int i = 0; i < 2; ++i) {
      int X = w * 2048 + i * 1024 + l * 16;
      int r = X >> 8, scb = (X & 255) ^ ((r & 7) << 4);
      gload_lds16(K + bbase + (size_t)r * DM + (scb >> 1), &Ks[0][(w * 2048 + i * 1024) >> 1]);
    }
#pragma unroll
    for (int i = 0; i < 2; ++i) {
      int X = w * 2048 + i * 1024 + l * 16;
      int d = X >> 7, scb = (X & 127) ^ ((d & 7) << 4);
      gload_lds16(vtb + (size_t)d * S_ + (scb >> 1), &Vs[0][(w * 2048 + i * 1024) >> 1]);
    }

    for (int kt = 0; kt <= ktmax; ++kt) {
      const int buf = kt & 1;
      if (kt < ktmax) {
        const int nk = (kt + 1) * 64;
#pragma unroll
        for (int i = 0; i < 2; ++i) {
          int X = w * 2048 + i * 1024 + l * 16;
          int r = X >> 8, scb = (X & 255) ^ ((r & 7) << 4);
          gload_lds16(K + bbase + (size_t)(nk + r) * DM + (scb >> 1),
                      &Ks[buf ^ 1][(w * 2048 + i * 1024) >> 1]);
        }
#pragma unroll
        for (int i = 0; i < 2; ++i) {
          int X = w * 2048 + i * 1024 + l * 16;
          int d = X >> 7, scb = (X & 127) ^ ((d & 7) << 4);
          gload_lds16(vtb + (size_t)d * S_ + nk + (scb >> 1),
                      &Vs[buf ^ 1][(w * 2048 + i * 1024) >> 1]);
        }
        asm volatile("s_waitcnt vmcnt(4)" ::: "memory");
      } else {
        asm volatile("s_waitcnt vmcnt(0)" ::: "memory");
      }
      __builtin_amdgcn_s_barrier();

      f32x4 sc4[4];
      __builtin_amdgcn_s_setprio(1);
#pragma unroll
      for (int cb = 0; cb < 4; ++cb) {
        sc4[cb] = f32x4{0.f, 0.f, 0.f, 0.f};
        int r = cb * 16 + lr;
#pragma unroll
        for (int kb = 0; kb < 4; ++kb) {
          int off = r * 256 + ((kb * 64 + lg * 16) ^ ((lr & 7) << 4));
          bf16x8 kf = *reinterpret_cast<const bf16x8*>((const char*)Ks[buf] + off);
          sc4[cb] = __builtin_amdgcn_mfma_f32_16x16x32_bf16(kf, qf[kb], sc4[cb], 0, 0, 0);
        }
      }
      __builtin_amdgcn_s_setprio(0);

      const int kv0 = kt * 64;
      if (kv0 + 63 > q0) {
        const int qq = q0 + lr;
#pragma unroll
        for (int cb = 0; cb < 4; ++cb)
#pragma unroll
          for (int jj = 0; jj < 4; ++jj)
            if (kv0 + cb * 16 + lg * 4 + jj > qq) sc4[cb][jj] = -INFINITY;
      }

      float tm = -INFINITY;
#pragma unroll
      for (int cb = 0; cb < 4; ++cb)
#pragma unroll
        for (int jj = 0; jj < 4; ++jj) tm = fmaxf(tm, sc4[cb][jj]);
      tm = fmaxf(tm, __shfl_xor(tm, 16));
      tm = fmaxf(tm, __shfl_xor(tm, 32));
      const bool resc = !__all(tm <= m_r + 8.0f);
      float sc_f = 1.f;
      if (resc) {
        float mnew = fmaxf(m_r, tm);
        sc_f = __expf(m_r - mnew);
        m_r = mnew;
      }
      float rs = 0.f;
#pragma unroll
      for (int cb = 0; cb < 4; ++cb)
#pragma unroll
        for (int jj = 0; jj < 4; ++jj) {
          float pp = __expf(sc4[cb][jj] - m_r);
          sc4[cb][jj] = pp;
          rs += pp;
        }
      rs += __shfl_xor(rs, 16);
      rs += __shfl_xor(rs, 32);
      l_r = l_r * sc_f + rs;
      if (resc) {
        float scO[4];
#pragma unroll
        for (int j = 0; j < 4; ++j) scO[j] = __shfl(sc_f, lg * 4 + j);
#pragma unroll
        for (int nb = 0; nb < 8; ++nb)
#pragma unroll
          for (int j = 0; j < 4; ++j) o[nb][j] *= scO[j];
      }

#pragma unroll
      for (int cb = 0; cb < 4; ++cb) {
        bf16x4 pk = { (bf16)sc4[cb][0], (bf16)sc4[cb][1], (bf16)sc4[cb][2], (bf16)sc4[cb][3] };
        int off = lr * 128 + ((cb * 32 + lg * 8) ^ ((lr & 7) << 4));
        *reinterpret_cast<bf16x4*>((char*)Ps[w] + off) = pk;
      }

      bf16x8 pf[2];
#pragma unroll
      for (int kc = 0; kc < 2; ++kc) {
        int off = lr * 128 + ((kc * 64 + lg * 16) ^ ((lr & 7) << 4));
        pf[kc] = *reinterpret_cast<const bf16x8*>((const char*)Ps[w] + off);
      }
      __builtin_amdgcn_s_setprio(1);
#pragma unroll
      for (int nb = 0; nb < 8; ++nb) {
        int d = nb * 16 + lr;
#pragma unroll
        for (int kc = 0; kc < 2; ++kc) {
          int off = d * 128 + ((kc * 64 + lg * 16) ^ ((lr & 7) << 4));
          bf16x8 vf = *reinterpret_cast<const bf16x8*>((const char*)Vs[buf] + off);
          o[nb] = __builtin_amdgcn_mfma_f32_16x16x32_bf16(pf[kc], vf, o[nb], 0, 0, 0);
        }
      }
      __builtin_amdgcn_s_setprio(0);

      asm volatile("s_waitcnt lgkmcnt(0)" ::: "memory");
      __builtin_amdgcn_s_barrier();
    }

    float lO[4];
#pragma unroll
    for (int j = 0; j < 4; ++j) lO[j] = __shfl(l_r, lg * 4 + j);
#pragma unroll
    for (int j = 0; j < 4; ++j) {
      float inv = 1.0f / lO[j];
      size_t rowoff = bbase + (size_t)(q0 + lg * 4 + j) * DM;
#pragma unroll
      for (int nb = 0; nb < 8; ++nb)
        O[rowoff + nb * 16 + lr] = (bf16)(o[nb][j] * inv);
    }
  }
}

extern "C" void kernel_launch(void* const* d_in, const int* in_sizes, int n_in,
                              void* d_out, int out_size, void* d_ws, size_t ws_size,
                              hipStream_t stream) {
  const float* x  = (const float*)d_in[0];
  const float* Wq = (const float*)d_in[1];
  const float* Wk = (const float*)d_in[2];
  const float* Wv = (const float*)d_in[3];
  const float* Wo = (const float*)d_in[4];
  const float* bo = (const float*)d_in[5];
  float* out = (float*)d_out;

  const size_t NX = (size_t)B_ * S_ * DM;  // 16,777,216
  const size_t NW = (size_t)DM * DM;       //  4,194,304
  char* ws = (char*)d_ws;
  bf16* xb   = (bf16*)ws; ws += NX * 2;
  bf16* wqkv = (bf16*)ws; ws += 3 * NW * 2;  // [Wq;Wk;Wv] as one [6144][2048]
  bf16* wob  = (bf16*)ws; ws += NW * 2;
  bf16* qb   = (bf16*)ws; ws += NX * 2;
  bf16* kb   = (bf16*)ws; ws += NX * 2;
  bf16* vt   = (bf16*)ws; ws += NX * 2;   // V pre-transposed [B][H][HD][S]
  bf16* ctxb = (bf16*)ws; ws += NX * 2;
  float* tab = (float*)ws; ws += (size_t)S_ * 64 * 2 * sizeof(float);

  cast_all<<<2048, 256, 0, stream>>>(x, Wq, Wk, Wv, Wo, xb, wqkv, wob);
  rope_table_k<<<(S_ * 64 + 255) / 256, 256, 0, stream>>>(tab);

  const int M = B_ * S_;
  // fused QKV projection + RoPE + V-transpose: C[8192][6144]
  gemm16d<0><<<dim3(3 * DM / 256, M / 256), 512, 0, stream>>>(
      xb, wqkv, qb, kb, vt, nullptr, nullptr, tab, 3 * DM, DM);

  attn_fwd<<<dim3(8, H_, B_), 512, 0, stream>>>(qb, kb, vt, ctxb);

  // output projection + bias (f32 out)
  gemm16d<1><<<dim3(DM / 256, M / 256), 512, 0, stream>>>(
      ctxb, wob, nullptr, nullptr, nullptr, out, bo, nullptr, DM, DM);
}